// Round 11
// baseline (59.598 us; speedup 1.0000x reference)
//
#include <hip/hip_runtime.h>
#include <hip/hip_bf16.h>

#define N_TOK   32768       // 8 * 4096 tokens
#define DPROJ   1024
#define SCALE   32.0f       // sqrt(1024) — only used in the naive fallback

typedef short bf16x8 __attribute__((ext_vector_type(8)));
typedef float f32x4  __attribute__((ext_vector_type(4)));

__device__ __forceinline__ short f2bf(float f) {
    unsigned u = __builtin_bit_cast(unsigned, f);
    unsigned r = (u + 0x7FFFu + ((u >> 16) & 1u)) >> 16;   // RNE
    return (short)r;
}

// ---------------------------------------------------------------------------
// Fused prep kernel.
//   blocks [0,128):   bucketize (wave-ballot aggregated, 4 atomics per wave)
//   blocks [128,896): transpose+convert proj -> projT[n][k] bf16, PRE-SCALED
//                     by 32 (exact: power-of-2 scale commutes with bf16 RNE).
// ---------------------------------------------------------------------------
__global__ void k_prep(const int* __restrict__ inp, int* __restrict__ cnt,
                       int* __restrict__ perm, int* __restrict__ rowidx,
                       const float* __restrict__ p0, const float* __restrict__ p1,
                       const float* __restrict__ p2, const float* __restrict__ p3,
                       short* __restrict__ t0, short* __restrict__ t1,
                       short* __restrict__ t2, short* __restrict__ t3)
{
    __shared__ float tile[128][17];

    if (blockIdx.x < 128) {
        int i = blockIdx.x * 256 + threadIdx.x;
        int t = inp[i];
        int b, l;
        if (t < 20000)       { b = 0; l = 0; }
        else if (t < 40000)  { b = 1; l = 20000; }
        else if (t < 200000) { b = 2; l = 40000; }
        else                 { b = 3; l = 200000; }

        unsigned long long m0 = __ballot(b == 0);
        unsigned long long m1 = __ballot(b == 1);
        unsigned long long m2 = __ballot(b == 2);
        unsigned long long m3 = __ballot(b == 3);

        int lane = threadIdx.x & 63;
        int mybase = 0;
        if (lane < 4) {
            unsigned long long mm = (lane == 0) ? m0 : (lane == 1) ? m1 : (lane == 2) ? m2 : m3;
            mybase = atomicAdd(&cnt[lane], __popcll(mm));
        }
        int base = __shfl(mybase, b);
        unsigned long long mine = (b == 0) ? m0 : (b == 1) ? m1 : (b == 2) ? m2 : m3;
        unsigned long long lt = (lane == 0) ? 0ull : (~0ull >> (64 - lane));
        int pos = base + __popcll(mine & lt);
        perm[b * N_TOK + pos]   = i;
        rowidx[b * N_TOK + pos] = t - l;
        return;
    }

    int bid = blockIdx.x - 128;
    const float* src; short* dst; int K; int rel;
    if (bid < 512)      { src = p0; dst = t0; K = 1024; rel = bid; }
    else if (bid < 640) { src = p1; dst = t1; K = 256;  rel = bid - 512; }
    else if (bid < 704) { src = p2; dst = t2; K = 64;   rel = bid - 640; }
    else                { src = p3; dst = t3; K = 16;   rel = bid - 704; }
    int ktiles = (K + 127) >> 7;
    int k0 = (rel % ktiles) * 128;
    int n0 = (rel / ktiles) * 16;
    int t = threadIdx.x;

    #pragma unroll
    for (int i = 0; i < 2; ++i) {
        int idx = t + i * 256;
        int k = idx >> 2;
        int nc = (idx & 3) * 4;
        if (k0 + k < K) {
            float4 v = *reinterpret_cast<const float4*>(src + (size_t)(k0 + k) * DPROJ + n0 + nc);
            tile[k][nc + 0] = v.x; tile[k][nc + 1] = v.y;
            tile[k][nc + 2] = v.z; tile[k][nc + 3] = v.w;
        }
    }
    __syncthreads();
    int n  = t >> 4;
    int kc = (t & 15) * 8;
    if (k0 + kc < K) {
        short s[8];
        #pragma unroll
        for (int j = 0; j < 8; ++j) s[j] = f2bf(tile[kc + j][n] * 32.0f);
        *reinterpret_cast<int4*>(dst + (size_t)(n0 + n) * K + k0 + kc) =
            *reinterpret_cast<const int4*>(s);
    }
}

// ---------------------------------------------------------------------------
// DEEP path (K=1024/256): R7 proven structure. BM=64, BN=256, BK=32,
// 512 thr, A+B LDS, T14 one-ahead regs, two barriers per K-step.
// ---------------------------------------------------------------------------
template<int K>
__device__ __forceinline__ void body_deep(
    const float* __restrict__ emb, const short* __restrict__ bt,
    int M, int m0, const int* __restrict__ pperm, const int* __restrict__ prow,
    int n0, float* __restrict__ out,
    short (&As)[64][40], short (&Bs)[256][40])
{
    const int tid  = threadIdx.x;
    const int lane = tid & 63;
    const int w    = tid >> 6;
    const int ar   = tid >> 3;
    const int ac   = (tid & 7) * 4;
    const int br   = tid >> 1;
    const int bh   = (tid & 1) * 16;
    const bool avalid = (m0 + ar) < M;
    const int  arow   = avalid ? prow[m0 + ar] : 0;
    const float* aptr = emb + (size_t)arow * K;

    const int koff = (lane >> 4) * 8;
    const int fr   = lane & 15;
    const int rowg = (lane >> 4) * 4;

    int pr[4][4];
    #pragma unroll
    for (int mi = 0; mi < 4; ++mi)
        #pragma unroll
        for (int j = 0; j < 4; ++j) {
            int m = m0 + mi * 16 + rowg + j;
            pr[mi][j] = (m < M) ? pperm[m] : 0;
        }

    f32x4 acc[4][2];
    #pragma unroll
    for (int mi = 0; mi < 4; ++mi)
        #pragma unroll
        for (int ni = 0; ni < 2; ++ni) acc[mi][ni] = (f32x4)0.0f;

    float4 av;
    int4   bv0, bv1;
#define ISSUE_LOADS(K0)                                                        \
    {                                                                          \
        av = avalid ? *reinterpret_cast<const float4*>(aptr + (K0) + ac)       \
                    : make_float4(0.f, 0.f, 0.f, 0.f);                         \
        const short* bp = bt + (size_t)(n0 + br) * K + (K0) + bh;              \
        bv0 = *reinterpret_cast<const int4*>(bp);                              \
        bv1 = *reinterpret_cast<const int4*>(bp + 8);                          \
    }

    ISSUE_LOADS(0);
    for (int k0 = 0; k0 < K; k0 += 32) {
        __syncthreads();
        {
            short asv[4];
            asv[0] = f2bf(av.x); asv[1] = f2bf(av.y);
            asv[2] = f2bf(av.z); asv[3] = f2bf(av.w);
            *reinterpret_cast<int2*>(&As[ar][ac]) = *reinterpret_cast<const int2*>(asv);
            *reinterpret_cast<int4*>(&Bs[br][bh])     = bv0;
            *reinterpret_cast<int4*>(&Bs[br][bh + 8]) = bv1;
        }
        if (k0 + 32 < K) ISSUE_LOADS(k0 + 32);
        __syncthreads();

        bf16x8 afr[4], bfr[2];
        #pragma unroll
        for (int mi = 0; mi < 4; ++mi)
            afr[mi] = *reinterpret_cast<const bf16x8*>(&As[mi * 16 + fr][koff]);
        #pragma unroll
        for (int ni = 0; ni < 2; ++ni)
            bfr[ni] = *reinterpret_cast<const bf16x8*>(&Bs[w * 32 + ni * 16 + fr][koff]);
        #pragma unroll
        for (int mi = 0; mi < 4; ++mi)
            #pragma unroll
            for (int ni = 0; ni < 2; ++ni)
                acc[mi][ni] = __builtin_amdgcn_mfma_f32_16x16x32_bf16(
                    afr[mi], bfr[ni], acc[mi][ni], 0, 0, 0);
    }
#undef ISSUE_LOADS

    const int colb = n0 + w * 32 + fr;
    #pragma unroll
    for (int mi = 0; mi < 4; ++mi) {
        #pragma unroll
        for (int j = 0; j < 4; ++j) {
            int m = m0 + mi * 16 + rowg + j;
            if (m < M) {
                size_t r = (size_t)pr[mi][j] * DPROJ + colb;
                out[r]      = acc[mi][0][j];      // B pre-scaled by 32
                out[r + 16] = acc[mi][1][j];
            }
        }
    }
}

// ---------------------------------------------------------------------------
// SHORT path (K=64/16): single-shot. B-frags direct from global into regs
// (issued first); A staged once through LDS; ONE barrier; MFMA; store.
// ---------------------------------------------------------------------------
template<int K>
__device__ __forceinline__ void body_short(
    const float* __restrict__ emb, const short* __restrict__ bt,
    int M, int m0, const int* __restrict__ pperm, const int* __restrict__ prow,
    int n0, float* __restrict__ out,
    short (&As)[64][40], short (&Bs)[256][40])
{
    constexpr int NKF = (K == 64) ? 2 : 1;

    const int tid  = threadIdx.x;
    const int lane = tid & 63;
    const int w    = tid >> 6;
    const int koff = (lane >> 4) * 8;
    const int fr   = lane & 15;
    const int rowg = (lane >> 4) * 4;

    int pr[4][4];
    #pragma unroll
    for (int mi = 0; mi < 4; ++mi)
        #pragma unroll
        for (int j = 0; j < 4; ++j) {
            int m = m0 + mi * 16 + rowg + j;
            pr[mi][j] = (m < M) ? pperm[m] : 0;
        }

    // ---- B fragments: direct from global (issued first, L2-resident) ----
    const short* btw = bt + (size_t)(n0 + w * 32 + fr) * K;
    bf16x8 bfr[2][NKF];
    #pragma unroll
    for (int ni = 0; ni < 2; ++ni)
        #pragma unroll
        for (int kf = 0; kf < NKF; ++kf) {
            if (K == 16 && koff >= 16)
                bfr[ni][kf] = (bf16x8)0;
            else
                bfr[ni][kf] = *reinterpret_cast<const bf16x8*>(
                    btw + (size_t)ni * 16 * K + kf * 32 + koff);
        }

    f32x4 acc[4][2];
    #pragma unroll
    for (int mi = 0; mi < 4; ++mi)
        #pragma unroll
        for (int ni = 0; ni < 2; ++ni) acc[mi][ni] = (f32x4)0.0f;

    if constexpr (K == 64) {
        // A64 aliased into Bs: [64][72] (stride 144B -> uniform banks on b128)
        short (*As2)[72] = reinterpret_cast<short(*)[72]>(&Bs[0][0]);  // 9.2 KB
        const int row = tid >> 3;
        const int c   = (tid & 7) * 8;
        const bool av = (m0 + row) < M;
        const int  ar = av ? prow[m0 + row] : 0;
        const float* ap = emb + (size_t)ar * 64 + c;
        float4 x = *reinterpret_cast<const float4*>(ap);
        float4 y = *reinterpret_cast<const float4*>(ap + 4);
        short s[8];
        s[0] = f2bf(x.x); s[1] = f2bf(x.y); s[2] = f2bf(x.z); s[3] = f2bf(x.w);
        s[4] = f2bf(y.x); s[5] = f2bf(y.y); s[6] = f2bf(y.z); s[7] = f2bf(y.w);
        *reinterpret_cast<int4*>(&As2[row][c]) = *reinterpret_cast<const int4*>(s);
        __syncthreads();

        #pragma unroll
        for (int mi = 0; mi < 4; ++mi) {
            bf16x8 afr0 = *reinterpret_cast<const bf16x8*>(&As2[mi * 16 + fr][koff]);
            bf16x8 afr1 = *reinterpret_cast<const bf16x8*>(&As2[mi * 16 + fr][32 + koff]);
            #pragma unroll
            for (int ni = 0; ni < 2; ++ni) {
                acc[mi][ni] = __builtin_amdgcn_mfma_f32_16x16x32_bf16(
                    afr0, bfr[ni][0], acc[mi][ni], 0, 0, 0);
                acc[mi][ni] = __builtin_amdgcn_mfma_f32_16x16x32_bf16(
                    afr1, bfr[ni][1], acc[mi][ni], 0, 0, 0);
            }
        }
    } else {    // K == 16: BK=32 layout in As, upper half zero-filled
        const int row = tid >> 3;
        const int c   = (tid & 7) * 4;
        if (c < 16) {
            const bool av = (m0 + row) < M;
            const int  ar = av ? prow[m0 + row] : 0;
            float4 x = *reinterpret_cast<const float4*>(emb + (size_t)ar * 16 + c);
            short s[4];
            s[0] = f2bf(x.x); s[1] = f2bf(x.y); s[2] = f2bf(x.z); s[3] = f2bf(x.w);
            *reinterpret_cast<int2*>(&As[row][c]) = *reinterpret_cast<const int2*>(s);
        } else {
            int z[2] = {0, 0};
            *reinterpret_cast<int2*>(&As[row][c]) = *reinterpret_cast<const int2*>(z);
        }
        __syncthreads();

        #pragma unroll
        for (int mi = 0; mi < 4; ++mi) {
            bf16x8 afr = *reinterpret_cast<const bf16x8*>(&As[mi * 16 + fr][koff]);
            #pragma unroll
            for (int ni = 0; ni < 2; ++ni)
                acc[mi][ni] = __builtin_amdgcn_mfma_f32_16x16x32_bf16(
                    afr, bfr[ni][0], acc[mi][ni], 0, 0, 0);
        }
    }

    const int colb = n0 + w * 32 + fr;
    #pragma unroll
    for (int mi = 0; mi < 4; ++mi) {
        #pragma unroll
        for (int j = 0; j < 4; ++j) {
            int m = m0 + mi * 16 + rowg + j;
            if (m < M) {
                size_t r = (size_t)pr[mi][j] * DPROJ + colb;
                out[r]      = acc[mi][0][j];      // B pre-scaled by 32
                out[r + 16] = acc[mi][1][j];
            }
        }
    }
}

// ---------------------------------------------------------------------------
// Fused GEMM dispatch: deep (K=1024/256) + short (K=64/16) block paths.
// Grid 4x520, XCD remap: all 4 n-panels of a row-tile on the same XCD.
// ---------------------------------------------------------------------------
__global__ __launch_bounds__(512, 4) void k_gemm(
    const float* __restrict__ e0, const float* __restrict__ e1,
    const float* __restrict__ e2, const float* __restrict__ e3,
    const short* __restrict__ t0, const short* __restrict__ t1,
    const short* __restrict__ t2, const short* __restrict__ t3,
    const int* __restrict__ cnt, const int* __restrict__ perm,
    const int* __restrict__ rowidx, float* __restrict__ out)
{
    __shared__ short As[64][40];
    __shared__ short Bs[256][40];

    const int hw    = blockIdx.y * 4 + blockIdx.x;
    const int ytile = (hw >> 5) * 8 + (hw & 7);
    const int panel = (hw >> 3) & 3;

    const int c0 = cnt[0], c1 = cnt[1], c2 = cnt[2], c3 = cnt[3];
    const int q0 = (c0 + 63) & ~63;
    const int q1 = q0 + ((c1 + 63) & ~63);
    const int q2 = q1 + ((c2 + 63) & ~63);
    const int q3 = q2 + ((c3 + 63) & ~63);
    const int p0 = ytile * 64;
    if (p0 >= q3) return;
    const int n0 = panel * 256;

    if (p0 < q0) {
        body_deep<1024>(e0, t0, c0, p0, perm, rowidx, n0, out, As, Bs);
    } else if (p0 < q1) {
        body_deep<256>(e1, t1, c1, p0 - q0, perm + N_TOK, rowidx + N_TOK,
                       n0, out, As, Bs);
    } else if (p0 < q2) {
        body_short<64>(e2, t2, c2, p0 - q1, perm + 2 * N_TOK,
                       rowidx + 2 * N_TOK, n0, out, As, Bs);
    } else {
        body_short<16>(e3, t3, c3, p0 - q2, perm + 3 * N_TOK,
                       rowidx + 3 * N_TOK, n0, out, As, Bs);
    }
}

// ---------------------------------------------------------------------------
// Fallback (ws too small): one block per token, direct fp32 dot products.
// ---------------------------------------------------------------------------
__global__ void k_naive(const int* __restrict__ inp,
                        const float* __restrict__ emb0, const float* __restrict__ emb1,
                        const float* __restrict__ emb2, const float* __restrict__ emb3,
                        const float* __restrict__ proj0, const float* __restrict__ proj1,
                        const float* __restrict__ proj2, const float* __restrict__ proj3,
                        float* __restrict__ out)
{
    __shared__ float e[1024];
    int t = inp[blockIdx.x];
    const float* emb; const float* proj; int K, l;
    if (t < 20000)       { emb = emb0; proj = proj0; K = 1024; l = 0; }
    else if (t < 40000)  { emb = emb1; proj = proj1; K = 256;  l = 20000; }
    else if (t < 200000) { emb = emb2; proj = proj2; K = 64;   l = 40000; }
    else                 { emb = emb3; proj = proj3; K = 16;   l = 200000; }
    int tid = threadIdx.x;
    for (int k = tid; k < K; k += 256) e[k] = emb[(size_t)(t - l) * K + k];
    __syncthreads();
    float acc[4] = {0.f, 0.f, 0.f, 0.f};
    for (int k = 0; k < K; ++k) {
        float ek = e[k];
        #pragma unroll
        for (int c = 0; c < 4; ++c)
            acc[c] = fmaf(ek, proj[(size_t)k * DPROJ + tid + 256 * c], acc[c]);
    }
    #pragma unroll
    for (int c = 0; c < 4; ++c)
        out[(size_t)blockIdx.x * DPROJ + tid + 256 * c] = acc[c] * SCALE;
}

extern "C" void kernel_launch(void* const* d_in, const int* in_sizes, int n_in,
                              void* d_out, int out_size, void* d_ws, size_t ws_size,
                              hipStream_t stream) {
    const int*   inp   = (const int*)d_in[0];
    const float* emb0  = (const float*)d_in[1];
    const float* proj0 = (const float*)d_in[2];
    const float* emb1  = (const float*)d_in[3];
    const float* proj1 = (const float*)d_in[4];
    const float* emb2  = (const float*)d_in[5];
    const float* proj2 = (const float*)d_in[6];
    const float* emb3  = (const float*)d_in[7];
    const float* proj3 = (const float*)d_in[8];
    float* out = (float*)d_out;

    const size_t off_cnt  = 0;
    const size_t off_perm = 256;
    const size_t off_row  = off_perm + 4ull * N_TOK * 4;
    const size_t off_t0   = off_row  + 4ull * N_TOK * 4;
    const size_t off_t1   = off_t0 + 1024ull * 1024 * 2;
    const size_t off_t2   = off_t1 + 1024ull * 256 * 2;
    const size_t off_t3   = off_t2 + 1024ull * 64 * 2;
    const size_t needed   = off_t3 + 1024ull * 16 * 2;

    if (d_ws == nullptr || ws_size < needed) {
        k_naive<<<N_TOK, 256, 0, stream>>>(inp, emb0, emb1, emb2, emb3,
                                           proj0, proj1, proj2, proj3, out);
        return;
    }

    char* ws = (char*)d_ws;
    int*   cnt    = (int*)(ws + off_cnt);
    int*   perm   = (int*)(ws + off_perm);
    int*   rowidx = (int*)(ws + off_row);
    short* t0     = (short*)(ws + off_t0);
    short* t1     = (short*)(ws + off_t1);
    short* t2     = (short*)(ws + off_t2);
    short* t3     = (short*)(ws + off_t3);

    hipMemsetAsync(cnt, 0, 16, stream);
    k_prep<<<896, 256, 0, stream>>>(inp, cnt, perm, rowidx,
                                    proj0, proj1, proj2, proj3, t0, t1, t2, t3);

    dim3 grid(4, 520);      // bijective mod-8 XCD remap (65 complete chunks)
    k_gemm<<<grid, 512, 0, stream>>>(emb0, emb1, emb2, emb3,
                                     t0, t1, t2, t3,
                                     cnt, perm, rowidx, out);
}